// Round 10
// baseline (43.725 us; speedup 1.0000x reference)
//
#include <hip/hip_runtime.h>
#include <hip/hip_bf16.h>

// BERT_CRF single-kernel: R2's champion K1 (40.07 us as K1+K2) with the
// per-batch fold fused via FENCE-FREE device-scope atomics.
// B=64, T=512, H=768, L=9.
//
// Why previous fusions failed: R1 (full __threadfence per block) and R8
// (RELEASE fetch_add per block) both attach L2 writeback/invalidate ops to
// the handoff -- 256+ cache-maintenance ops thrash all 8 XCD L2s while
// other blocks stream wv. This version publishes the ~100 floats/block with
// RELAXED AGENT-scope atomic stores (global_store ... sc1: write-through to
// the coherence point, NO cache maintenance), uses __syncthreads()'s
// documented vmcnt(0) drain for ordering, then a RELAXED per-batch counter.
// 4th-arriving quarter-block folds its batch (proven comb math, relaxed
// agent atomic loads), stores partial[b] atomically; second relaxed
// election picks the final 64-value reducer. No fences, no spins.
//
// K1 body (emissions + chunk products + 8->4->2->1 combine) is R2 VERBATIM.
// bcnt[64]+cnt2 zeroed by a 260-B hipMemsetAsync (workspace is poisoned).

#define Bn 64
#define Tn 512
#define Hn 768
#define Ln 9
#define EMS 12     // padded emission row stride (floats)
#define CS 16      // time steps per chunk
#define NCHQ 8     // chunks per quarter
#define QT 128     // timesteps per block
#define KSTEPS 24  // 768 / 32

typedef short bf16x8 __attribute__((ext_vector_type(8)));   // 8 bf16 (4 VGPRs)
typedef float f32x4  __attribute__((ext_vector_type(4)));   // 4 fp32 acc

__device__ __forceinline__ short f2bf(float f) {
    return (short)__builtin_bit_cast(unsigned short, __float2bfloat16(f));
}

__device__ __forceinline__ void ast(float* p, float v) {
    __hip_atomic_store(p, v, __ATOMIC_RELAXED, __HIP_MEMORY_SCOPE_AGENT);
}
__device__ __forceinline__ void asti(int* p, int v) {
    __hip_atomic_store(p, v, __ATOMIC_RELAXED, __HIP_MEMORY_SCOPE_AGENT);
}
__device__ __forceinline__ float ald(const float* p) {
    return __hip_atomic_load(p, __ATOMIC_RELAXED, __HIP_MEMORY_SCOPE_AGENT);
}
__device__ __forceinline__ int aldi(const int* p) {
    return __hip_atomic_load(p, __ATOMIC_RELAXED, __HIP_MEMORY_SCOPE_AGENT);
}

// ---------------- fused kernel: grid 256 = (b, quarter), 512 thr ----------------
__global__ __launch_bounds__(512) void emis_q_kernel(
    const float* __restrict__ wv, const float* __restrict__ Wm,
    const float* __restrict__ bias, const int* __restrict__ mask,
    const int* __restrict__ label, const float* __restrict__ trans,
    const float* __restrict__ startT, const float* __restrict__ endT,
    float* __restrict__ Mq, float* __restrict__ lgq,
    float* __restrict__ numq, int* __restrict__ msq,
    float* __restrict__ em0, float* __restrict__ partial,
    int* __restrict__ bcnt, int* __restrict__ cnt2,
    float* __restrict__ out)
{
    __shared__ bf16x8 wlds[KSTEPS * 64];     // 24576 B, W B-fragments
    __shared__ float  ldsE[QT][EMS];         // exp(emissions), 6144 B
    __shared__ int    ldsM[QT];              // mask slice
    __shared__ float  eTs[81];               // exp(transitions)
    __shared__ float  sM[NCHQ][Ln][Ln];      // chunk product matrices
    __shared__ float  sLg[NCHQ][Ln];         // chunk row log-scales
    __shared__ float  sp[8];
    __shared__ int    si[8];
    __shared__ int    sOld;

    const int tid   = threadIdx.x;
    const int lane  = tid & 63;
    const int wid   = tid >> 6;
    const int bid   = blockIdx.x;
    const int b     = bid >> 2;
    const int q     = bid & 3;
    const int tbase = q * QT;

    if (tid < 81) eTs[tid] = __expf(trans[tid]);

    // Stage W (L=9 x H=768 fp32) as bf16 B-fragments in MFMA lane order:
    // entry (kk, lane): lane holds B[k = kk*32 + (lane>>4)*8 + j][n = lane&15],
    // B[k][n] = W[n][k]; n >= 9 -> zeros.  (R2 verbatim)
    for (int idx = tid; idx < KSTEPS * 64; idx += 512) {
        const int kk = idx >> 6, ln = idx & 63;
        const int n = ln & 15, kb2 = ln >> 4;
        bf16x8 v;
        if (n < Ln) {
            const float* src = Wm + n * Hn + kk * 32 + kb2 * 8;
#pragma unroll
            for (int j = 0; j < 8; ++j) v[j] = f2bf(src[j]);
        } else {
#pragma unroll
            for (int j = 0; j < 8; ++j) v[j] = 0;
        }
        wlds[idx] = v;
    }
    __syncthreads();

    // ---- emission phase: wave wid computes rows [bid*128 + wid*16, +16) ----
    {
        const int m  = lane & 15;            // A row within tile
        const int kb = lane >> 4;            // k-subblock (8 elems)
        const float* abase = wv + (size_t)(bid * QT + wid * 16 + m) * Hn + kb * 8;

        f32x4 acc = {0.f, 0.f, 0.f, 0.f};
#pragma unroll 4
        for (int kk = 0; kk < KSTEPS; ++kk) {
            float4 x0 = *reinterpret_cast<const float4*>(abase + kk * 32);
            float4 x1 = *reinterpret_cast<const float4*>(abase + kk * 32 + 4);
            bf16x8 a;
            a[0] = f2bf(x0.x); a[1] = f2bf(x0.y); a[2] = f2bf(x0.z); a[3] = f2bf(x0.w);
            a[4] = f2bf(x1.x); a[5] = f2bf(x1.y); a[6] = f2bf(x1.z); a[7] = f2bf(x1.w);
            bf16x8 bfr = wlds[kk * 64 + lane];
            acc = __builtin_amdgcn_mfma_f32_16x16x32_bf16(a, bfr, acc, 0, 0, 0);
        }
        // C/D layout: col = lane&15, row = (lane>>4)*4 + r. Write exp to LDS.
        const int l = lane & 15;
        if (l < Ln) {
            const float bl = bias[l];
#pragma unroll
            for (int r = 0; r < 4; ++r) {
                const int lrow = wid * 16 + (lane >> 4) * 4 + r;
                ldsE[lrow][l] = __expf(acc[r] + bl);
            }
        }
    }
    __syncthreads();

    // ---- numerator partials + mask staging (threads 0..127; R2 verbatim) ----
    float part = 0.f; int ms = 0;
    if (tid < QT) {
        const int gt  = tbase + tid;
        const int tag = label[b * Tn + gt];
        const int mk  = mask[b * Tn + gt];
        ldsM[tid] = mk; ms = mk;
        if (gt == 0) {
            part = startT[tag] + __logf(ldsE[0][tag]);
        } else if (mk) {
            const int prev = label[b * Tn + gt - 1];
            part = trans[prev * Ln + tag] + __logf(ldsE[tid][tag]);
        }
    }
#pragma unroll
    for (int off = 32; off > 0; off >>= 1) {
        part += __shfl_xor(part, off);
        ms   += __shfl_xor(ms, off);
    }
    if (lane == 0) { sp[wid] = part; si[wid] = ms; }
    __syncthreads();

    // ---- chunk products (threads 0..71; R2 verbatim) ----
    if (tid < NCHQ * Ln) {
        float Tr[81];
#pragma unroll
        for (int i = 0; i < 81; ++i) Tr[i] = eTs[i];
        const int r = tid % Ln;
        const int c = tid / Ln;

        float v[9];
#pragma unroll
        for (int k = 0; k < 9; ++k) v[k] = (k == r) ? 1.f : 0.f;
        float lg = 0.f;

        int t0 = tbase + c * CS; if (t0 == 0) t0 = 1;   // only (q==0,c==0)
        const int t1 = tbase + (c + 1) * CS;

        int lt = t0 - tbase;
        float4 e0v = *reinterpret_cast<const float4*>(&ldsE[lt][0]);
        float4 e1v = *reinterpret_cast<const float4*>(&ldsE[lt][4]);
        float  e8  = ldsE[lt][8];
        int    mk  = ldsM[lt];

        for (int t = t0; t < t1; ++t) {
            float4 p0 = make_float4(0.f, 0.f, 0.f, 0.f), p1 = p0;
            float  p8 = 0.f; int pm = 0;
            if (t + 1 < t1) {
                const int nlt = t + 1 - tbase;
                p0 = *reinterpret_cast<const float4*>(&ldsE[nlt][0]);
                p1 = *reinterpret_cast<const float4*>(&ldsE[nlt][4]);
                p8 = ldsE[nlt][8];
                pm = ldsM[nlt];
            }
            if (mk) {
                float e[9] = {e0v.x, e0v.y, e0v.z, e0v.w, e1v.x, e1v.y, e1v.z, e1v.w, e8};
                float nv[9];
#pragma unroll
                for (int jj = 0; jj < 9; ++jj) {
                    float acc = v[0] * Tr[jj];
#pragma unroll
                    for (int k = 1; k < 9; ++k) acc += v[k] * Tr[k * 9 + jj];
                    nv[jj] = acc * e[jj];
                }
                float mx = nv[0];
#pragma unroll
                for (int jj = 1; jj < 9; ++jj) mx = fmaxf(mx, nv[jj]);
                float inv = 1.f / mx;
#pragma unroll
                for (int jj = 0; jj < 9; ++jj) v[jj] = nv[jj] * inv;
                lg += __logf(mx);
            }
            e0v = p0; e1v = p1; e8 = p8; mk = pm;
        }
#pragma unroll
        for (int jj = 0; jj < 9; ++jj) sM[c][r][jj] = v[jj];
        sLg[c][r] = lg;
    }
    // parallel small outputs -- published with agent-scope atomic stores
    if (q == 0 && tid >= 72 && tid < 81) ast(&em0[b * Ln + (tid - 72)], ldsE[0][tid - 72]);
    if (tid == 100) {
        float s = 0.f; int m2 = 0;
#pragma unroll
        for (int i = 0; i < 8; ++i) { s += sp[i]; m2 += si[i]; }
        ast(&numq[bid], s); asti(&msq[bid], m2);
    }
    __syncthreads();

    // ---- pair-combine 8 -> 4 -> 2 (in place; R2 verbatim) ----
    for (int n = 4; n >= 2; n >>= 1) {
        float vout[9]; float lgout = 0.f;
        const bool act = tid < n * Ln;
        int p = 0, r = 0;
        if (act) {
            p = tid / Ln; r = tid % Ln;
            float mB = sLg[2 * p + 1][0];
#pragma unroll
            for (int k = 1; k < 9; ++k) mB = fmaxf(mB, sLg[2 * p + 1][k]);
            float tA[9];
#pragma unroll
            for (int k = 0; k < 9; ++k) tA[k] = sM[2 * p][r][k] * __expf(sLg[2 * p + 1][k] - mB);
#pragma unroll
            for (int jj = 0; jj < 9; ++jj) {
                float acc = tA[0] * sM[2 * p + 1][0][jj];
#pragma unroll
                for (int k = 1; k < 9; ++k) acc += tA[k] * sM[2 * p + 1][k][jj];
                vout[jj] = acc;
            }
            float mx = vout[0];
#pragma unroll
            for (int jj = 1; jj < 9; ++jj) mx = fmaxf(mx, vout[jj]);
            float inv = 1.f / mx;
#pragma unroll
            for (int jj = 0; jj < 9; ++jj) vout[jj] *= inv;
            lgout = sLg[2 * p][r] + mB + __logf(mx);
        }
        __syncthreads();
        if (act) {
#pragma unroll
            for (int jj = 0; jj < 9; ++jj) sM[p][r][jj] = vout[jj];
            sLg[p][r] = lgout;
        }
        __syncthreads();
    }

    // ---- final pair -> quarter matrix, published via atomic stores ----
    if (tid < Ln) {
        const int r = tid;
        float mB = sLg[1][0];
#pragma unroll
        for (int k = 1; k < 9; ++k) mB = fmaxf(mB, sLg[1][k]);
        float tA[9];
#pragma unroll
        for (int k = 0; k < 9; ++k) tA[k] = sM[0][r][k] * __expf(sLg[1][k] - mB);
        float v[9];
#pragma unroll
        for (int jj = 0; jj < 9; ++jj) {
            float acc = tA[0] * sM[1][0][jj];
#pragma unroll
            for (int k = 1; k < 9; ++k) acc += tA[k] * sM[1][k][jj];
            v[jj] = acc;
        }
        float mx = v[0];
#pragma unroll
        for (int jj = 1; jj < 9; ++jj) mx = fmaxf(mx, v[jj]);
        float inv = 1.f / mx;
#pragma unroll
        for (int jj = 0; jj < 9; ++jj) ast(&Mq[bid * 81 + r * 9 + jj], v[jj] * inv);
        ast(&lgq[bid * Ln + r], sLg[0][r] + mB + __logf(mx));
    }

    // ---- per-batch election (fence-free) ----
    // __syncthreads codegen drains vmcnt(0) per wave -> all sc1 stores of
    // this block are at the coherence point before the counter bump.
    __syncthreads();
    if (tid == 0)
        sOld = __hip_atomic_fetch_add(&bcnt[b], 1, __ATOMIC_RELAXED,
                                      __HIP_MEMORY_SCOPE_AGENT);
    __syncthreads();
    if (sOld != 3) return;

    // ---- batch finisher: fold 4 quarter matrices (proven comb math) ----
    if (tid < 16) {
        const int lj = tid;
        const float NEG = -1e30f;
        float la = (lj < Ln) ? (startT[lj] + __logf(ald(&em0[b * Ln + lj]))) : NEG;
        for (int c = 0; c < 4; ++c) {
            const float* Mc = Mq + (b * 4 + c) * 81;
            float mc[9];
#pragma unroll
            for (int rr = 0; rr < 9; ++rr) mc[rr] = (lj < Ln) ? ald(&Mc[rr * 9 + lj]) : 0.f;
            float x = (lj < Ln) ? (la + ald(&lgq[(b * 4 + c) * Ln + lj])) : NEG;
            float mm = x;
#pragma unroll
            for (int off = 1; off < 16; off <<= 1) mm = fmaxf(mm, __shfl_xor(mm, off, 16));
            float w = __expf(x - mm);                 // lj>=9 -> 0
            float sacc = 0.f;
#pragma unroll
            for (int rr = 0; rr < 9; ++rr) sacc += __shfl(w, rr, 16) * mc[rr];
            la = (lj < Ln) ? (mm + __logf(sacc)) : NEG;
        }
        float x = (lj < Ln) ? (la + endT[lj]) : NEG;
        float mm = x;
#pragma unroll
        for (int off = 1; off < 16; off <<= 1) mm = fmaxf(mm, __shfl_xor(mm, off, 16));
        float se = __expf(x - mm);
#pragma unroll
        for (int off = 1; off < 16; off <<= 1) se += __shfl_xor(se, off, 16);
        if (lj == 0) {
            float denom = mm + __logf(se);
            float numer = ald(&numq[b * 4 + 0]) + ald(&numq[b * 4 + 1])
                        + ald(&numq[b * 4 + 2]) + ald(&numq[b * 4 + 3]);
            int   sm    = aldi(&msq[b * 4 + 0]) + aldi(&msq[b * 4 + 1])
                        + aldi(&msq[b * 4 + 2]) + aldi(&msq[b * 4 + 3]);
            int   last  = label[b * Tn + sm - 1];
            ast(&partial[b], denom - (numer + endT[last]));   // = -llh[b]
        }
    }

    // ---- final election over 64 batch finishers (fence-free) ----
    __syncthreads();    // drains the partial[b] sc1 store
    if (tid == 0)
        sOld = __hip_atomic_fetch_add(cnt2, 1, __ATOMIC_RELAXED,
                                      __HIP_MEMORY_SCOPE_AGENT);
    __syncthreads();
    if (sOld != Bn - 1) return;

    if (tid < 64) {
        float pv = ald(&partial[tid]);
#pragma unroll
        for (int off = 32; off > 0; off >>= 1) pv += __shfl_xor(pv, off);
        if (tid == 0) out[0] = pv * (1.0f / Bn);
    }
}

extern "C" void kernel_launch(void* const* d_in, const int* in_sizes, int n_in,
                              void* d_out, int out_size, void* d_ws, size_t ws_size,
                              hipStream_t stream)
{
    // inputs: 0=length(unused) 1=word2vec 2=mask 3=label 4=W 5=b 6=start 7=end 8=trans
    const float* wv    = (const float*)d_in[1];
    const int*   mask  = (const int*)d_in[2];
    const int*   label = (const int*)d_in[3];
    const float* Wm    = (const float*)d_in[4];
    const float* bias  = (const float*)d_in[5];
    const float* st    = (const float*)d_in[6];
    const float* en    = (const float*)d_in[7];
    const float* tr    = (const float*)d_in[8];

    float* ws      = (float*)d_ws;
    float* Mq      = ws;                   // 256*81 = 20736
    float* lgq     = ws + 20736;           // 256*9  = 2304
    float* numq    = ws + 23040;           // 256
    int*   msq     = (int*)(ws + 23296);   // 256
    float* em0     = ws + 23552;           // 64*9 = 576
    float* partial = ws + 24128;           // 64
    int*   bcnt    = (int*)(ws + 24192);   // 64 per-batch counters
    int*   cnt2    = bcnt + Bn;            // final-election counter
    float* out     = (float*)d_out;

    // workspace poisoned between iterations: zero the election counters
    hipMemsetAsync(bcnt, 0, (Bn + 1) * sizeof(int), stream);

    hipLaunchKernelGGL(emis_q_kernel, dim3(256), dim3(512), 0, stream,
                       wv, Wm, bias, mask, label, tr, st, en,
                       Mq, lgq, numq, msq, em0, partial, bcnt, cnt2, out);
}